// Round 3
// baseline (182.124 us; speedup 1.0000x reference)
//
#include <hip/hip_runtime.h>
#include <float.h>

#define NB 8
#define CIN 64
#define NPTS 16384
#define KNB 9
#define COUT 128
#define TN 64          // columns per main-kernel block
#define FPAD 65        // feat leading-dim pad: (c+lane)%32 -> 2-way (free on CDNA4)

// ---------------- prep: transpose x [B][64][N] -> xt [B][N][64], W [o][c] -> Wt [c][o]
__global__ __launch_bounds__(256) void prep_kernel(const float* __restrict__ x,
                                                   const float* __restrict__ W,
                                                   float* __restrict__ xt,
                                                   float* __restrict__ Wt) {
    int blk = blockIdx.x;
    if (blk == NB * (NPTS / 64)) {
        // transpose W (128x128) -> Wt[c][o]
        for (int i = threadIdx.x; i < COUT * 2 * CIN; i += 256) {
            int o = i >> 7;
            int c = i & 127;
            Wt[c * COUT + o] = W[i];
        }
        return;
    }
    __shared__ float t[64][65];
    int b   = blk >> 8;            // 256 tiles per batch
    int n0  = (blk & 255) << 6;
    int tid = threadIdx.x;
    int hi  = tid >> 4;            // 0..15
    int lo  = tid & 15;            // 0..15
    const float* xb = x + (size_t)b * CIN * NPTS;

    // phase 1: float4 loads along n; ds_write_b32 banks (c+4lo+j)%32 -> 2-way free
#pragma unroll
    for (int cc = 0; cc < 4; ++cc) {
        int c = cc * 16 + hi;
        int n = lo * 4;
        float4 v = *reinterpret_cast<const float4*>(&xb[(size_t)c * NPTS + n0 + n]);
        t[c][n + 0] = v.x; t[c][n + 1] = v.y; t[c][n + 2] = v.z; t[c][n + 3] = v.w;
    }
    __syncthreads();

    // phase 2: ds_read_b32 banks (4lo+j+n)%32 -> 2-way free; float4 coalesced store
    float* xtb = xt + (size_t)b * NPTS * 64;
#pragma unroll
    for (int it = 0; it < 4; ++it) {
        int n  = it * 16 + hi;
        int c4 = lo * 4;
        float4 v;
        v.x = t[c4 + 0][n]; v.y = t[c4 + 1][n]; v.z = t[c4 + 2][n]; v.w = t[c4 + 3][n];
        *reinterpret_cast<float4*>(&xtb[(size_t)(n0 + n) * 64 + c4]) = v;
    }
}

// ---------------- main: gather + max-rel aggr + GEMM(128x128 @ 128x64) + bias + relu
__global__ __launch_bounds__(256, 4) void mrconv_main(const float* __restrict__ x,
                                                      const int*   __restrict__ eidx,
                                                      const float* __restrict__ Wt,
                                                      const float* __restrict__ bias,
                                                      const float* __restrict__ xt,
                                                      float* __restrict__ out) {
    __shared__ float feat[2 * CIN][FPAD];

    int blk  = blockIdx.x;
    int b    = blk & 7;          // batch == XCD id under round-robin dispatch (L2 locality)
    int tile = blk >> 3;
    int n0   = tile * TN;

    int tid  = threadIdx.x;
    int lane = tid & 63;
    int wid  = __builtin_amdgcn_readfirstlane(tid >> 6);   // force wave-uniform

    const float* xb  = x  + (size_t)b * CIN * NPTS;
    const float* xtb = xt + (size_t)b * NPTS * 64;
    const int*   eb  = eidx + ((size_t)b * NPTS + n0) * KNB;  // edge_index[0][b][n0..][k]

    // stage x-part: feat[c][n], c in 0..63  (coalesced along n; 2-way free banks)
#pragma unroll
    for (int i = 0; i < 16; ++i) {
        int c = wid * 16 + i;
        feat[c][lane] = xb[(size_t)c * NPTS + n0 + lane];
    }
    __syncthreads();   // gather phase reads x-part staged by other waves

    // gather + max-relative: lane = channel, wave iterates columns n = i*4 + wid
#pragma unroll 2
    for (int i = 0; i < 16; ++i) {
        int n = i * 4 + wid;
        float xc = feat[lane][n];                        // staged x, LDS (2-way free)
        const int* ep = eb + n * KNB;                    // wave-uniform -> s_load
        float m = -FLT_MAX;
#pragma unroll
        for (int k = 0; k < KNB; ++k) {
            int j = ep[k];
            float xj = xtb[(size_t)j * 64 + lane];       // 256B coalesced, L2-resident
            m = fmaxf(m, xj - xc);
        }
        feat[CIN + lane][n] = m;                         // banks (lane+n)%32: 2-way free
    }
    __syncthreads();

    // GEMM: wave 'wid' computes output rows [wid*32, wid*32+32) for all 64 columns
    int o_base = wid * 32;
    float acc[32];
#pragma unroll
    for (int oo = 0; oo < 32; ++oo) acc[oo] = 0.f;

    for (int c = 0; c < 2 * CIN; ++c) {
        float f = feat[c][lane];                         // 1 ds_read_b32, free banks
        const float* wrow = Wt + c * COUT + o_base;      // wave-uniform -> s_load
#pragma unroll
        for (int oo = 0; oo < 32; ++oo)
            acc[oo] = fmaf(wrow[oo], f, acc[oo]);        // v_fmac_f32 with SGPR operand
    }

    // epilogue: bias + relu, coalesced 256B stores
    float* ob = out + (size_t)b * COUT * NPTS + n0;
#pragma unroll
    for (int oo = 0; oo < 32; ++oo) {
        int o = o_base + oo;
        float v = acc[oo] + bias[o];
        ob[(size_t)o * NPTS + lane] = fmaxf(v, 0.f);
    }
}

// ---------------- fallback (no workspace): direct gather from x, W un-transposed.
// Slow (uncoalesced gathers) but correct and writes ONLY d_out.
__global__ __launch_bounds__(256) void mrconv_direct(const float* __restrict__ x,
                                                     const int*   __restrict__ eidx,
                                                     const float* __restrict__ W,
                                                     const float* __restrict__ bias,
                                                     float* __restrict__ out) {
    __shared__ float feat[2 * CIN][FPAD];

    int blk  = blockIdx.x;
    int b    = blk & 7;
    int tile = blk >> 3;
    int n0   = tile * TN;

    int tid  = threadIdx.x;
    int lane = tid & 63;
    int wid  = __builtin_amdgcn_readfirstlane(tid >> 6);

    const float* xb = x + (size_t)b * CIN * NPTS;
    const int*   eb = eidx + ((size_t)b * NPTS + n0) * KNB;

#pragma unroll
    for (int i = 0; i < 16; ++i) {
        int c = wid * 16 + i;
        feat[c][lane] = xb[(size_t)c * NPTS + n0 + lane];
    }
    __syncthreads();

    // lane = channel; per-lane stride NPTS -> uncoalesced but correct
    const float* xc_row = xb + (size_t)lane * NPTS;
#pragma unroll 2
    for (int i = 0; i < 16; ++i) {
        int n = i * 4 + wid;
        float xc = feat[lane][n];
        const int* ep = eb + n * KNB;
        float m = -FLT_MAX;
#pragma unroll
        for (int k = 0; k < KNB; ++k) {
            int j = ep[k];
            m = fmaxf(m, xc_row[j] - xc);
        }
        feat[CIN + lane][n] = m;
    }
    __syncthreads();

    int o_base = wid * 32;
    float acc[32];
#pragma unroll
    for (int oo = 0; oo < 32; ++oo) acc[oo] = 0.f;

    for (int c = 0; c < 2 * CIN; ++c) {
        float f = feat[c][lane];
#pragma unroll
        for (int oo = 0; oo < 32; ++oo)
            acc[oo] = fmaf(W[(o_base + oo) * (2 * CIN) + c], f, acc[oo]);  // uniform s_load
    }

    float* ob = out + (size_t)b * COUT * NPTS + n0;
#pragma unroll
    for (int oo = 0; oo < 32; ++oo) {
        int o = o_base + oo;
        float v = acc[oo] + bias[o];
        ob[(size_t)o * NPTS + lane] = fmaxf(v, 0.f);
    }
}

extern "C" void kernel_launch(void* const* d_in, const int* in_sizes, int n_in,
                              void* d_out, int out_size, void* d_ws, size_t ws_size,
                              hipStream_t stream) {
    const float* x    = (const float*)d_in[0];
    const int*   eidx = (const int*)  d_in[1];
    const float* W    = (const float*)d_in[2];
    const float* bias = (const float*)d_in[3];
    float*       out  = (float*)d_out;

    // workspace layout: xt (B*N*64 f32 = 32 MiB) | Wt (128*128 f32 = 64 KiB)
    const size_t need = ((size_t)NB * NPTS * 64 + (size_t)2 * CIN * COUT) * sizeof(float);

    if (ws_size >= need) {
        float* xt = (float*)d_ws;
        float* Wt = xt + (size_t)NB * NPTS * 64;

        dim3 blkA(256), grdA(NB * (NPTS / 64) + 1);   // +1 block transposes W
        hipLaunchKernelGGL(prep_kernel, grdA, blkA, 0, stream, x, W, xt, Wt);

        dim3 blkB(256), grdB(NB * (NPTS / TN));       // 2048 blocks, batch = blk & 7
        hipLaunchKernelGGL(mrconv_main, grdB, blkB, 0, stream, x, eidx, Wt, bias, xt, out);
    } else {
        dim3 blkB(256), grdB(NB * (NPTS / TN));
        hipLaunchKernelGGL(mrconv_direct, grdB, blkB, 0, stream, x, eidx, W, bias, out);
    }
}

// Round 4
// 144.134 us; speedup vs baseline: 1.2636x; 1.2636x over previous
//
#include <hip/hip_runtime.h>
#include <float.h>

#define NB 8
#define CIN 64
#define NPTS 16384
#define KNB 9
#define COUT 128
#define TN 64          // columns per main-kernel block
#define FPAD 65        // fallback feat pad
#define LDB 136        // bf16 LDS row: 128 + 8 pad -> 272B stride, 2-way banks (free)

typedef float f32x4 __attribute__((ext_vector_type(4)));
typedef __bf16 bf16x8 __attribute__((ext_vector_type(8)));

__device__ __forceinline__ ushort f2bf_rne(float f) {
    unsigned u = __float_as_uint(f);
    unsigned r = u + 0x7FFFu + ((u >> 16) & 1u);
    return (ushort)(r >> 16);
}
__device__ __forceinline__ float bf2f(ushort h) {
    return __uint_as_float(((unsigned)h) << 16);
}

// ---------------- prep: transpose x [B][64][N] -> xt [B][N][64]; W f32 -> Whi/Wlo bf16
__global__ __launch_bounds__(256) void prep_kernel(const float* __restrict__ x,
                                                   const float* __restrict__ W,
                                                   float* __restrict__ xt,
                                                   ushort* __restrict__ Whi,
                                                   ushort* __restrict__ Wlo) {
    int blk = blockIdx.x;
    if (blk == NB * (NPTS / 64)) {
        // split W (128x128, row-major kept) into bf16 hi/lo planes
        for (int i = threadIdx.x; i < COUT * 2 * CIN; i += 256) {
            float w = W[i];
            ushort h = f2bf_rne(w);
            Whi[i] = h;
            Wlo[i] = f2bf_rne(w - bf2f(h));
        }
        return;
    }
    __shared__ float t[64][65];
    int b   = blk >> 8;            // 256 tiles per batch
    int n0  = (blk & 255) << 6;
    int tid = threadIdx.x;
    int hi  = tid >> 4;            // 0..15
    int lo  = tid & 15;            // 0..15
    const float* xb = x + (size_t)b * CIN * NPTS;

#pragma unroll
    for (int cc = 0; cc < 4; ++cc) {
        int c = cc * 16 + hi;
        int n = lo * 4;
        float4 v = *reinterpret_cast<const float4*>(&xb[(size_t)c * NPTS + n0 + n]);
        t[c][n + 0] = v.x; t[c][n + 1] = v.y; t[c][n + 2] = v.z; t[c][n + 3] = v.w;
    }
    __syncthreads();

    float* xtb = xt + (size_t)b * NPTS * 64;
#pragma unroll
    for (int it = 0; it < 4; ++it) {
        int n  = it * 16 + hi;
        int c4 = lo * 4;
        float4 v;
        v.x = t[c4 + 0][n]; v.y = t[c4 + 1][n]; v.z = t[c4 + 2][n]; v.w = t[c4 + 3][n];
        *reinterpret_cast<float4*>(&xtb[(size_t)(n0 + n) * 64 + c4]) = v;
    }
}

// ---------------- main: gather + max-rel aggr + split-bf16 MFMA GEMM + bias + relu
__global__ __launch_bounds__(256, 4) void mrconv_main(const int*    __restrict__ eidx,
                                                      const ushort* __restrict__ Whi,
                                                      const ushort* __restrict__ Wlo,
                                                      const float*  __restrict__ bias,
                                                      const float*  __restrict__ xt,
                                                      float*        __restrict__ out) {
    // feat transposed [n][c] as bf16 hi/lo planes; pad 8 -> 272B row stride (free banks)
    __shared__ __align__(16) ushort fhi[TN][LDB];
    __shared__ __align__(16) ushort flo[TN][LDB];

    int blk  = blockIdx.x;
    int b    = blk & 7;          // batch == XCD id (gather table L2-resident per XCD)
    int tile = blk >> 3;
    int n0   = tile * TN;

    int tid  = threadIdx.x;
    int lane = tid & 63;
    int wid  = __builtin_amdgcn_readfirstlane(tid >> 6);
    int l16  = lane & 15;
    int lh   = lane >> 4;

    const float* xtb = xt + (size_t)b * NPTS * 64;
    const int*   eb  = eidx + ((size_t)b * NPTS + n0) * KNB;

    // ---- gather + max-relative; lane = channel, wave owns columns [wid*16, wid*16+16)
#pragma unroll 2
    for (int i = 0; i < 16; ++i) {
        int n = wid * 16 + i;
        float xc = xtb[(size_t)(n0 + n) * 64 + lane];        // 256B coalesced
        ushort xh = f2bf_rne(xc);
        fhi[n][lane] = xh;
        flo[n][lane] = f2bf_rne(xc - bf2f(xh));
        const int* ep = eb + n * KNB;                        // wave-uniform -> s_load
        float m = -FLT_MAX;
#pragma unroll
        for (int k = 0; k < KNB; ++k) {
            int j = ep[k];
            float xj = xtb[(size_t)j * 64 + lane];           // 256B coalesced, L2-hit
            m = fmaxf(m, xj - xc);
        }
        ushort mh = f2bf_rne(m);
        fhi[n][CIN + lane] = mh;
        flo[n][CIN + lane] = f2bf_rne(m - bf2f(mh));
    }

    // ---- A-fragment preload (global, LDS-independent -> overlaps gather tail)
    // A[o][c]: row = wid*32 + mt*16 + l16, k = kb*32 + lh*8 .. +7 (contiguous bf16x8)
    bf16x8 ahi[2][4], alo[2][4];
#pragma unroll
    for (int mt = 0; mt < 2; ++mt)
#pragma unroll
        for (int kb = 0; kb < 4; ++kb) {
            int off = (wid * 32 + mt * 16 + l16) * (2 * CIN) + kb * 32 + lh * 8;
            ahi[mt][kb] = *reinterpret_cast<const bf16x8*>(Whi + off);
            alo[mt][kb] = *reinterpret_cast<const bf16x8*>(Wlo + off);
        }

    __syncthreads();

    // ---- MFMA GEMM: wave computes out rows [wid*32, wid*32+32) x 64 cols
    f32x4 acc[2][4];
#pragma unroll
    for (int mt = 0; mt < 2; ++mt)
#pragma unroll
        for (int nt = 0; nt < 4; ++nt)
            acc[mt][nt] = (f32x4){0.f, 0.f, 0.f, 0.f};

#pragma unroll
    for (int nt = 0; nt < 4; ++nt) {
#pragma unroll
        for (int kb = 0; kb < 4; ++kb) {
            // B[k][n]: col = l16 (feat row n), k = kb*32 + lh*8 contiguous -> b128
            const bf16x8 bhi = *reinterpret_cast<const bf16x8*>(&fhi[nt * 16 + l16][kb * 32 + lh * 8]);
            const bf16x8 blo = *reinterpret_cast<const bf16x8*>(&flo[nt * 16 + l16][kb * 32 + lh * 8]);
#pragma unroll
            for (int mt = 0; mt < 2; ++mt) {
                acc[mt][nt] = __builtin_amdgcn_mfma_f32_16x16x32_bf16(ahi[mt][kb], bhi, acc[mt][nt], 0, 0, 0);
                acc[mt][nt] = __builtin_amdgcn_mfma_f32_16x16x32_bf16(ahi[mt][kb], blo, acc[mt][nt], 0, 0, 0);
                acc[mt][nt] = __builtin_amdgcn_mfma_f32_16x16x32_bf16(alo[mt][kb], bhi, acc[mt][nt], 0, 0, 0);
            }
        }
    }

    // ---- epilogue: C layout col=l16, row=lh*4+r (verified m89/m91); bias + relu
    float* ob = out + (size_t)b * COUT * NPTS + n0;
#pragma unroll
    for (int mt = 0; mt < 2; ++mt)
#pragma unroll
        for (int nt = 0; nt < 4; ++nt)
#pragma unroll
            for (int r = 0; r < 4; ++r) {
                int o = wid * 32 + mt * 16 + lh * 4 + r;
                int n = nt * 16 + l16;
                float v = acc[mt][nt][r] + bias[o];
                ob[(size_t)o * NPTS + n] = fmaxf(v, 0.f);   // 64B segments x4 rows
            }
}

// ---------------- fallback (no workspace): direct f32 path, writes ONLY d_out
__global__ __launch_bounds__(256) void mrconv_direct(const float* __restrict__ x,
                                                     const int*   __restrict__ eidx,
                                                     const float* __restrict__ W,
                                                     const float* __restrict__ bias,
                                                     float* __restrict__ out) {
    __shared__ float feat[2 * CIN][FPAD];

    int blk  = blockIdx.x;
    int b    = blk & 7;
    int tile = blk >> 3;
    int n0   = tile * TN;

    int tid  = threadIdx.x;
    int lane = tid & 63;
    int wid  = __builtin_amdgcn_readfirstlane(tid >> 6);

    const float* xb = x + (size_t)b * CIN * NPTS;
    const int*   eb = eidx + ((size_t)b * NPTS + n0) * KNB;

#pragma unroll
    for (int i = 0; i < 16; ++i) {
        int c = wid * 16 + i;
        feat[c][lane] = xb[(size_t)c * NPTS + n0 + lane];
    }
    __syncthreads();

    const float* xc_row = xb + (size_t)lane * NPTS;
#pragma unroll 2
    for (int i = 0; i < 16; ++i) {
        int n = i * 4 + wid;
        float xc = feat[lane][n];
        const int* ep = eb + n * KNB;
        float m = -FLT_MAX;
#pragma unroll
        for (int k = 0; k < KNB; ++k) {
            int j = ep[k];
            m = fmaxf(m, xc_row[j] - xc);
        }
        feat[CIN + lane][n] = m;
    }
    __syncthreads();

    int o_base = wid * 32;
    float acc[32];
#pragma unroll
    for (int oo = 0; oo < 32; ++oo) acc[oo] = 0.f;

    for (int c = 0; c < 2 * CIN; ++c) {
        float f = feat[c][lane];
#pragma unroll
        for (int oo = 0; oo < 32; ++oo)
            acc[oo] = fmaf(W[(o_base + oo) * (2 * CIN) + c], f, acc[oo]);
    }

    float* ob = out + (size_t)b * COUT * NPTS + n0;
#pragma unroll
    for (int oo = 0; oo < 32; ++oo) {
        int o = o_base + oo;
        float v = acc[oo] + bias[o];
        ob[(size_t)o * NPTS + lane] = fmaxf(v, 0.f);
    }
}

extern "C" void kernel_launch(void* const* d_in, const int* in_sizes, int n_in,
                              void* d_out, int out_size, void* d_ws, size_t ws_size,
                              hipStream_t stream) {
    const float* x    = (const float*)d_in[0];
    const int*   eidx = (const int*)  d_in[1];
    const float* W    = (const float*)d_in[2];
    const float* bias = (const float*)d_in[3];
    float*       out  = (float*)d_out;

    // workspace: xt (B*N*64 f32 = 32 MiB) | Whi (32 KiB bf16) | Wlo (32 KiB bf16)
    const size_t xt_elems = (size_t)NB * NPTS * 64;
    const size_t need = xt_elems * sizeof(float) + (size_t)2 * 2 * CIN * COUT * sizeof(ushort);

    if (ws_size >= need) {
        float*  xt  = (float*)d_ws;
        ushort* Whi = (ushort*)(xt + xt_elems);
        ushort* Wlo = Whi + (size_t)2 * CIN * COUT;

        dim3 blkA(256), grdA(NB * (NPTS / 64) + 1);   // +1 block splits W
        hipLaunchKernelGGL(prep_kernel, grdA, blkA, 0, stream, x, W, xt, Whi, Wlo);

        dim3 blkB(256), grdB(NB * (NPTS / TN));       // 2048 blocks, batch = blk & 7
        hipLaunchKernelGGL(mrconv_main, grdB, blkB, 0, stream, eidx, Whi, Wlo, bias, xt, out);
    } else {
        dim3 blkB(256), grdB(NB * (NPTS / TN));
        hipLaunchKernelGGL(mrconv_direct, grdB, blkB, 0, stream, x, eidx, W, bias, out);
    }
}